// Round 5
// baseline (16.453 us; speedup 1.0000x reference)
//
#include <hip/hip_runtime.h>
#include <math.h>

// ---------------------------------------------------------------------------
// QuantumPureQCNN, fully collapsed to a bond-2 MPS transfer-matrix contraction.
//
// qubit q <-> state bit (15-q).  After H^16 + CZ-chain + per-qubit RZ*RY*RX:
//   psi(t) = 2^-8 * u . A_0(t0) A_1(t1) ... A_14(t14) . c(t15),   u=[1,1]
//   A_q(t) = [[U_q[t,0], U_q[t,0]], [U_q[t,1], -U_q[t,1]]]  (2x2, bond dim 2)
//   c(t)   = [U_15[t,0], U_15[t,1]]^T
// QCNN = V0 x V1 x V2 x V3 on nibbles (qubits 4n..4n+3),
//   V_n = G2_(b3,b1) * (G1a_(b3,b2) x G1b_(b1,b0)),  G = RY*CNOT*ZZ*YY*XX
//   (G has 8 nonzeros, closed form -- see Phase A).
// V is never materialized: pair products P(v) = A.A (1 cmul closed form),
//   H_{n,side}(u) = sum_v G1[u,v] P(v)           (2x2 bond matrices)
//   M_n(s)[a,b]   = sum_{m3,m1} G2[(s3s1),(m3m1)] (Ha(m3,s2).Hb(m1,s0))[a,b]
// Measurements (Z on each nibble's bit3) via doubled 4x4 transfer matrices:
//   D_n^w[(aa'),(bb')] = sum_s w(s) M_n(s)[a,b] conj(M_n(s)[a',b'])
//   E_o = [1,1,1,1] . D_0 D_1 D_2 . (D_3 col (0,0)) / 65536
// One kernel, one block per batch (32 x 256), ~6 KB LDS, no workspace.
// ---------------------------------------------------------------------------

struct C { float x, y; };
__device__ __forceinline__ C operator+(C a, C b){ return {a.x+b.x, a.y+b.y}; }
__device__ __forceinline__ C operator-(C a, C b){ return {a.x-b.x, a.y-b.y}; }
__device__ __forceinline__ C cmul(C a, C b){ return { a.x*b.x - a.y*b.y, a.x*b.y + a.y*b.x }; }
__device__ __forceinline__ C cfma(C a, C b, C acc){
  acc.x = fmaf(a.x, b.x, fmaf(-a.y, b.y, acc.x));
  acc.y = fmaf(a.x, b.y, fmaf( a.y, b.x, acc.y));
  return acc;
}
// acc += a * conj(b)
__device__ __forceinline__ C cfmac(C a, C b, C acc){
  acc.x = fmaf(a.x, b.x, fmaf( a.y, b.y, acc.x));
  acc.y = fmaf(a.y, b.x, fmaf(-a.x, b.y, acc.y));
  return acc;
}

__global__ __launch_bounds__(256) void qk_all(const float* __restrict__ x,
                                              const float* __restrict__ w,
                                              const float* __restrict__ Wm,
                                              const float* __restrict__ bias,
                                              float* __restrict__ outp)
{
  __shared__ C G[12][16];     // fused pair gates (8 nonzeros each)
  __shared__ C uL[64];        // 16 single-qubit 2x2 (RZ*RY*RX)
  __shared__ C sH[128];       // H_{n,side}(u)[a][b] : n*32+side*16+u*4+a*2+b
  __shared__ C sM[256];       // M_n(s)[a][b]        : n*64+s*4+a*2+b
  __shared__ C sSlo[64];      // half-sums of D_n    : n*16+p
  __shared__ C sShi[64];
  __shared__ float qv[4];

  const int tid = threadIdx.x;
  const int b   = blockIdx.x;

  // ------- Phase A: one lane per (pair, element) for G; wave 3 does U -------
  {
    int p = tid >> 4;                     // pair 0..11 on waves 0..2
    if (p < 12) {
      int idx = tid & 15, r = idx >> 2, c = idx & 3;
      float a0, a1, a2, ry;
      if (p < 8) { a0 = w[3*p];   a1 = w[3*p+1];  a2 = w[3*p+2];  ry = w[24+p]; }
      else { int n = p-8; a0 = w[32+3*n]; a1 = w[33+3*n]; a2 = w[34+3*n]; ry = w[44+n]; }
      float s0,c0,s1,c1,s2,c2,sr,cr;
      __sincosf(0.5f*a0, &s0, &c0);
      __sincosf(0.5f*a1, &s1, &c1);
      __sincosf(0.5f*a2, &s2, &c2);
      __sincosf(0.5f*ry, &sr, &cr);
      int rlo = r & 1, rhi = r >> 1;
      float d   = rlo ? fmaf(-s0, s1, c0*c1) : fmaf(s0, s1, c0*c1);
      float eps = rlo ? fmaf( c0, s1, c1*s0) : fmaf(-c0, s1, c1*s0);
      bool valid = rlo ? (c == 1 || c == 2) : (c == 0 || c == 3);
      bool sel   = rlo ? (c == 2) : (c == 3);
      float re, im;
      if (!sel) { re = rhi ?  sr*d : cr*d;  im = rhi ? -cr*eps :  sr*eps; }
      else      { re = rhi ?  cr*d : -sr*d; im = rhi ? -sr*eps : -cr*eps; }
      float zi = rlo ? s2 : -s2;                // z = (c2, +/- s2)
      C val;
      if (valid) val = { fmaf(re, c2, -im*zi), fmaf(re, zi, im*c2) };
      else       val = {0.f, 0.f};
      G[p][idx] = val;
    } else if (tid >= 192 && tid < 208) {       // wave 3: U_q = RZ*RY*RX
      int q = tid - 192;
      float h = 0.5f * x[b*16 + q];
      float s, c;
      __sincosf(h, &s, &c);
      C em = {c,-s}, ep = {c,s};
      C A00 = { c*c,  s*s}, A01 = {-c*s, -c*s};
      C A10 = { c*s, -c*s}, A11 = { c*c, -s*s};
      uL[q*4+0] = cmul(em, A00);
      uL[q*4+1] = cmul(em, A01);
      uL[q*4+2] = cmul(ep, A10);
      uL[q*4+3] = cmul(ep, A11);
    }
  }
  __syncthreads();

  // ------- Phase B1: H_{n,side}(u)[a][b] = sum_v G1[u,v] * (A.A)(v)[a][b] ---
  // Pair product closed form: P(v)[a][b] = u1[thi*2+a] * (u2[tlo*2+0] + coef*u2[tlo*2+1]),
  //   coef = sgn1(a)*sgn2(b); last pair of nibble 3 multiplies Chat (col 1 = 0).
  if (tid < 128) {
    int n = tid >> 5, side = (tid >> 4) & 1, u = (tid >> 2) & 3;
    int a = (tid >> 1) & 1, bb = tid & 1;
    int q1 = 4*n + 2*side;
    bool chat = (n == 3 && side == 1);
    float t1 = a ? -1.f : 1.f;
    float coef = (chat || !bb) ? t1 : -t1;
    bool zero = chat && bb;
    const C* g1 = &G[2*n + side][u*4];
    C acc{0,0};
    #pragma unroll
    for (int v=0; v<4; v++){
      C pv{0,0};
      if (!zero) {
        int thi = v >> 1, tlo = v & 1;
        C u1a = uL[q1*4 + thi*2 + a];
        C u20 = uL[q1*4 + 4 + tlo*2 + 0];
        C u21 = uL[q1*4 + 4 + tlo*2 + 1];
        C inner = { fmaf(coef, u21.x, u20.x), fmaf(coef, u21.y, u20.y) };
        pv = cmul(u1a, inner);
      }
      acc = cfma(g1[v], pv, acc);
    }
    sH[tid] = acc;    // layout == tid
  }
  __syncthreads();

  // ------- Phase B2: M_n(s)[a][b] via G2 on (Ha . Hb) ------------------------
  {
    int n = tid >> 6, s = (tid >> 2) & 15;
    int a = (tid >> 1) & 1, bb = tid & 1;
    int s3=(s>>3)&1, s2b=(s>>2)&1, s1=(s>>1)&1, s0=s&1;
    const C* g2 = &G[8+n][(s3*2+s1)*4];
    const C* hn = &sH[n*32];
    C acc{0,0};
    #pragma unroll
    for (int m3=0;m3<2;m3++)
    #pragma unroll
    for (int m1=0;m1<2;m1++){
      const C* Ha = &hn[(m3*2+s2b)*4];        // [a*2+c]
      const C* Hb = &hn[16 + (m1*2+s0)*4];    // [c*2+b]
      C X = cmul(Ha[a*2+0], Hb[bb]) + cmul(Ha[a*2+1], Hb[2+bb]);
      acc = cfma(g2[m3*2+m1], X, acc);
    }
    sM[tid] = acc;    // layout n*64 + s*4 + a*2 + b == tid
  }
  __syncthreads();

  // ------- Phase D: half-sums of doubled transfers ---------------------------
  if (tid < 128) {
    int h = tid >> 6, idx = tid & 63;
    int n = idx >> 4, p = idx & 15;
    int a=(p>>3)&1, a2=(p>>2)&1, bb=(p>>1)&1, b2=p&1;
    const C* mn = &sM[n<<6];
    C S{0,0};
    #pragma unroll
    for (int s=0;s<8;s++){
      int sc = (h*8 + s) << 2;
      S = cfmac(mn[sc+(a<<1)+bb], mn[sc+(a2<<1)+b2], S);
    }
    if (h) sShi[idx] = S; else sSlo[idx] = S;
  }
  __syncthreads();

  // ------- Phase E: 16-lane transfer-matrix chain ----------------------------
  // lane (o,j): v_j' = sum_i v_i * D_n[i][j],  D_n = Slo +/- Shi (Z if n==o)
  if (tid < 16) {
    int o = tid >> 2, j = tid & 3;
    int grp = tid & ~3;
    C v = {1.f, 0.f};
    #pragma unroll
    for (int n=0; n<3; n++){
      float sgn = (n==o) ? -1.f : 1.f;
      C nv{0,0};
      #pragma unroll
      for (int i=0;i<4;i++){
        C vi = { __shfl(v.x, grp+i), __shfl(v.y, grp+i) };
        int di = n*16 + i*4 + j;
        C D = { fmaf(sgn, sShi[di].x, sSlo[di].x),
                fmaf(sgn, sShi[di].y, sSlo[di].y) };
        nv = cfma(vi, D, nv);
      }
      v = nv;
    }
    float sgn3 = (o==3) ? -1.f : 1.f;
    int di = 48 + j*4;                       // D3[j][0]
    C D3 = { fmaf(sgn3, sShi[di].x, sSlo[di].x),
             fmaf(sgn3, sShi[di].y, sSlo[di].y) };
    C p = cmul(v, D3);
    p.x += __shfl_xor(p.x, 1);
    p.x += __shfl_xor(p.x, 2);
    if (j == 0) qv[o] = p.x * (1.0f/65536.0f);
  }
  __syncthreads();

  // ------- Phase F: linear head ----------------------------------------------
  if (tid < 9) {
    float acc = bias[tid];
    #pragma unroll
    for (int k=0;k<4;k++) acc = fmaf(qv[k], Wm[tid*4+k], acc);
    outp[b*9 + tid] = acc;
  }
}

// -----------------------------------------------------------------------------
extern "C" void kernel_launch(void* const* d_in, const int* in_sizes, int n_in,
                              void* d_out, int out_size, void* d_ws, size_t ws_size,
                              hipStream_t stream)
{
  (void)in_sizes; (void)n_in; (void)out_size; (void)d_ws; (void)ws_size;
  const float* x    = (const float*)d_in[0];   // [32][16]
  const float* w    = (const float*)d_in[1];   // [78]
  const float* Wm   = (const float*)d_in[2];   // [9][4]
  const float* bias = (const float*)d_in[3];   // [9]
  float* outp = (float*)d_out;                 // [32][9]

  qk_all<<<32, 256, 0, stream>>>(x, w, Wm, bias, outp);
}

// Round 6
// 9.749 us; speedup vs baseline: 1.6877x; 1.6877x over previous
//
#include <hip/hip_runtime.h>
#include <math.h>

// ---------------------------------------------------------------------------
// QuantumPureQCNN, fully collapsed to a bond-2 MPS transfer-matrix contraction.
//
// qubit q <-> state bit (15-q).  After H^16 + CZ-chain + per-qubit RZ*RY*RX:
//   psi(t) = 2^-8 * u . A_0(t0) A_1(t1) ... A_14(t14) . c(t15),   u=[1,1]
//   A_q(t) = [[U_q[t,0], U_q[t,0]], [U_q[t,1], -U_q[t,1]]]  (2x2, bond dim 2)
//   c(t)   = [U_15[t,0], U_15[t,1]]^T
// The QCNN circuit = V0 x V1 x V2 x V3 on the 4 nibbles (qubits 4n..4n+3),
//   V_n = G2_(b3,b1) * (G1a_(b3,b2) x G1b_(b1,b0)),  G = RY*CNOT*ZZ*YY*XX.
// G in closed form (8 nonzeros):
//   YY*XX = diag(d_i) + antidiag(-i eps_i), d = c0c1 +/- s0s1 (sign +--+),
//   eps = c1s0 -/+ c0s1; after ZZ (row z_i in {em,ep,ep,em}), CNOT row-swap,
//   RY(x)I:  rows {0,2} live in cols {0,3} scaled by em, rows {1,3} in cols
//   {1,2} scaled by ep, entries = {cr,sr} combos of d and -i*eps.
// Each V_n acts on 4 adjacent MPS sites -> boundary bonds stay dim 2:
//   M_n(s)[a,b] = sum_{s'} V_n[s,s'] * (A_{4n}..A_{4n+3})(s')[a,b]
// Measurements (Z on each nibble's bit3) via doubled 4x4 transfer matrices:
//   D_n^w[(aa'),(bb')] = sum_s w(s) M_n(s)[a,b] conj(M_n(s)[a',b'])
//   E_o = [1,1,1,1] . D_0 D_1 D_2 . (D_3 col (0,0)) / 65536
// One kernel, one block per batch (32 x 256), ~15 KB LDS, no workspace.
//
// NOTE (R5 post-mortem): the V-free restructure + __sincosf regressed
// 9.42 -> 16.45 us with no counter-visible cause; this is the exact R4
// best-known-good source. Do not re-apply R5's Phase B/C/E rewrite
// without isolating which half caused the regression.
// ---------------------------------------------------------------------------

struct C { float x, y; };
__device__ __forceinline__ C operator+(C a, C b){ return {a.x+b.x, a.y+b.y}; }
__device__ __forceinline__ C operator-(C a, C b){ return {a.x-b.x, a.y-b.y}; }
__device__ __forceinline__ C cmul(C a, C b){ return { a.x*b.x - a.y*b.y, a.x*b.y + a.y*b.x }; }
__device__ __forceinline__ C cfma(C a, C b, C acc){
  acc.x = fmaf(a.x, b.x, fmaf(-a.y, b.y, acc.x));
  acc.y = fmaf(a.x, b.y, fmaf( a.y, b.x, acc.y));
  return acc;
}
// acc += a * conj(b)
__device__ __forceinline__ C cfmac(C a, C b, C acc){
  acc.x = fmaf(a.x, b.x, fmaf( a.y, b.y, acc.x));
  acc.y = fmaf(a.y, b.x, fmaf(-a.x, b.y, acc.y));
  return acc;
}
__device__ __forceinline__ C cscale(C a, float s){ return {a.x*s, a.y*s}; }

__global__ __launch_bounds__(256) void qk_all(const float* __restrict__ x,
                                              const float* __restrict__ w,
                                              const float* __restrict__ Wm,
                                              const float* __restrict__ bias,
                                              float* __restrict__ outp)
{
  __shared__ C G[12][16];     // fused pair gates (sparse: 8 nonzeros each)
  __shared__ C uL[64];        // 16 single-qubit 2x2 (RZ*RY*RX)
  __shared__ C sV[1024];      // V_n [4][16][16]
  __shared__ C sT[256];       // site products [4][16][2][2]
  __shared__ C sM[256];       // M_n [4][16][2][2]
  __shared__ C sDp[64];       // D_n^+ [4][16]
  __shared__ C sDz[64];       // D_n^Z [4][16]
  __shared__ float qv[4];

  const int tid = threadIdx.x;
  const int b   = blockIdx.x;

  // ------- Phase A: one lane per (pair, element) for G; wave 3 does U -------
  {
    int p = tid >> 4;                     // pair 0..15 (12..15 unused for G)
    if (p < 12) {
      int idx = tid & 15, r = idx >> 2, c = idx & 3;
      float a0, a1, a2, ry;
      if (p < 8) { a0 = w[3*p];   a1 = w[3*p+1];  a2 = w[3*p+2];  ry = w[24+p]; }
      else { int n = p-8; a0 = w[32+3*n]; a1 = w[33+3*n]; a2 = w[34+3*n]; ry = w[44+n]; }
      float s0,c0,s1,c1,s2,c2,sr,cr;
      sincosf(0.5f*a0, &s0, &c0);
      sincosf(0.5f*a1, &s1, &c1);
      sincosf(0.5f*a2, &s2, &c2);
      sincosf(0.5f*ry, &sr, &cr);
      int rlo = r & 1, rhi = r >> 1;
      float d   = rlo ? fmaf(-s0, s1, c0*c1) : fmaf(s0, s1, c0*c1);
      float eps = rlo ? fmaf( c0, s1, c1*s0) : fmaf(-c0, s1, c1*s0);
      bool valid = rlo ? (c == 1 || c == 2) : (c == 0 || c == 3);
      bool sel   = rlo ? (c == 2) : (c == 3);   // first(diag-type) vs second
      float re, im;
      if (!sel) { re = rhi ?  sr*d : cr*d;  im = rhi ? -cr*eps :  sr*eps; }
      else      { re = rhi ?  cr*d : -sr*d; im = rhi ? -sr*eps : -cr*eps; }
      float zi = rlo ? s2 : -s2;                // z = (c2, +/- s2)
      C val;
      if (valid) val = { fmaf(re, c2, -im*zi), fmaf(re, zi, im*c2) };
      else       val = {0.f, 0.f};
      G[p][idx] = val;
    } else if (tid >= 192 && tid < 208) {       // wave 3: U_q = RZ*RY*RX
      int q = tid - 192;
      float h = 0.5f * x[b*16 + q];
      float s, c;
      sincosf(h, &s, &c);
      C em = {c,-s}, ep = {c,s};
      C A00 = { c*c,  s*s}, A01 = {-c*s, -c*s};
      C A10 = { c*s, -c*s}, A11 = { c*c, -s*s};
      uL[q*4+0] = cmul(em, A00);
      uL[q*4+1] = cmul(em, A01);
      uL[q*4+2] = cmul(ep, A10);
      uL[q*4+3] = cmul(ep, A11);
    }
  }
  __syncthreads();

  // ------- Phase B: assemble V_n (all 256) + site chains (lanes 0..63) ------
  {
    int lp = tid >> 4, lc = tid & 15;
    int p3=(lp>>3)&1, p2=(lp>>2)&1, p1=(lp>>1)&1, p0=lp&1;
    int l3=(lc>>3)&1, l2=(lc>>2)&1, l1=(lc>>1)&1, l0=lc&1;
    for (int n=0;n<4;n++){
      C acc{0,0};
      #pragma unroll
      for (int m3=0;m3<2;m3++)
      #pragma unroll
      for (int m1=0;m1<2;m1++){
        C g2 = G[8+n]  [(p3*2+p1)*4 + (m3*2+m1)];
        C ga = G[2*n]  [(m3*2+p2)*4 + (l3*2+l2)];
        C gb = G[2*n+1][(m1*2+p0)*4 + (l1*2+l0)];
        acc = cfma(g2, cmul(ga, gb), acc);
      }
      sV[n*256 + lp*16 + lc] = acc;
    }
  }
  if (tid < 64) {                 // T_n(s) = A_{4n}(t0) A(t1) A(t2) A/Chat(t3)
    int n = tid >> 4, s = tid & 15;
    int t0 = (s>>3)&1;
    C u0 = uL[(4*n)*4 + t0*2 + 0], u1 = uL[(4*n)*4 + t0*2 + 1];
    C P00=u0, P01=u0, P10=u1, P11={-u1.x,-u1.y};
    #pragma unroll
    for (int i=1;i<4;i++){
      int t = (s >> (3-i)) & 1;
      int q = 4*n + i;
      C v0 = uL[q*4 + t*2 + 0], v1 = uL[q*4 + t*2 + 1];
      C b00, b01, b10, b11;
      if (n == 3 && i == 3) { b00=v0; b01={0,0}; b10=v1; b11={0,0}; }   // Chat
      else { b00=v0; b01=v0; b10=v1; b11={-v1.x,-v1.y}; }               // A-form
      C n00 = cfma(P01, b10, cmul(P00, b00));
      C n01 = cfma(P01, b11, cmul(P00, b01));
      C n10 = cfma(P11, b10, cmul(P10, b00));
      C n11 = cfma(P11, b11, cmul(P10, b01));
      P00=n00; P01=n01; P10=n10; P11=n11;
    }
    int base = tid << 2;          // [n][s][a][b]
    sT[base+0]=P00; sT[base+1]=P01; sT[base+2]=P10; sT[base+3]=P11;
  }
  __syncthreads();

  // ------- Phase C: M_n(s)[a,b] = sum_{s'} V_n[s,s'] T_n(s')[a,b] -----------
  {
    int n = tid >> 6, s = (tid >> 2) & 15, ab = tid & 3;
    const C* vr = &sV[n*256 + s*16];
    const C* tn = &sT[(n<<6) + ab];
    C acc{0,0};
    #pragma unroll
    for (int k=0;k<16;k++) acc = cfma(vr[k], tn[k<<2], acc);
    sM[tid] = acc;
  }
  __syncthreads();

  // ------- Phase D: doubled transfers D_n^{+,Z} ------------------------------
  if (tid < 64) {
    int n = tid >> 4, p = tid & 15;
    int a=(p>>3)&1, a2=(p>>2)&1, bb=(p>>1)&1, b2=p&1;
    const C* mn = &sM[n<<6];
    C Slo{0,0}, Shi{0,0};
    #pragma unroll
    for (int s=0;s<8;s++)  Slo = cfmac(mn[(s<<2)+(a<<1)+bb], mn[(s<<2)+(a2<<1)+b2], Slo);
    #pragma unroll
    for (int s=8;s<16;s++) Shi = cfmac(mn[(s<<2)+(a<<1)+bb], mn[(s<<2)+(a2<<1)+b2], Shi);
    sDp[tid] = Slo + Shi;
    sDz[tid] = Slo - Shi;
  }
  __syncthreads();

  // ------- Phase E: contract 4 outputs ---------------------------------------
  if (tid < 4) {
    int o = tid;
    C v0={1,0}, v1={1,0}, v2={1,0}, v3={1,0};
    #pragma unroll
    for (int n=0;n<3;n++){
      const C* D = (n==o) ? &sDz[n<<4] : &sDp[n<<4];
      C n0{0,0}, n1{0,0}, n2{0,0}, n3{0,0};
      n0 = cfma(v0, D[ 0], n0); n0 = cfma(v1, D[ 4], n0); n0 = cfma(v2, D[ 8], n0); n0 = cfma(v3, D[12], n0);
      n1 = cfma(v0, D[ 1], n1); n1 = cfma(v1, D[ 5], n1); n1 = cfma(v2, D[ 9], n1); n1 = cfma(v3, D[13], n1);
      n2 = cfma(v0, D[ 2], n2); n2 = cfma(v1, D[ 6], n2); n2 = cfma(v2, D[10], n2); n2 = cfma(v3, D[14], n2);
      n3 = cfma(v0, D[ 3], n3); n3 = cfma(v1, D[ 7], n3); n3 = cfma(v2, D[11], n3); n3 = cfma(v3, D[15], n3);
      v0=n0; v1=n1; v2=n2; v3=n3;
    }
    const C* D3 = (o==3) ? &sDz[3<<4] : &sDp[3<<4];
    C e{0,0};                       // column (b,b') = (0,0)
    e = cfma(v0, D3[ 0], e); e = cfma(v1, D3[ 4], e);
    e = cfma(v2, D3[ 8], e); e = cfma(v3, D3[12], e);
    qv[o] = e.x * (1.0f/65536.0f);
  }
  __syncthreads();

  // ------- Phase F: linear head ----------------------------------------------
  if (tid < 9) {
    float acc = bias[tid];
    #pragma unroll
    for (int k=0;k<4;k++) acc = fmaf(qv[k], Wm[tid*4+k], acc);
    outp[b*9 + tid] = acc;
  }
}

// -----------------------------------------------------------------------------
extern "C" void kernel_launch(void* const* d_in, const int* in_sizes, int n_in,
                              void* d_out, int out_size, void* d_ws, size_t ws_size,
                              hipStream_t stream)
{
  (void)in_sizes; (void)n_in; (void)out_size; (void)d_ws; (void)ws_size;
  const float* x    = (const float*)d_in[0];   // [32][16]
  const float* w    = (const float*)d_in[1];   // [78]
  const float* Wm   = (const float*)d_in[2];   // [9][4]
  const float* bias = (const float*)d_in[3];   // [9]
  float* outp = (float*)d_out;                 // [32][9]

  qk_all<<<32, 256, 0, stream>>>(x, w, Wm, bias, outp);
}